// Round 5
// baseline (1124.305 us; speedup 1.0000x reference)
//
#include <hip/hip_runtime.h>

// VQ-VAE VectorQuantizer forward + EMA update, MI355X (gfx950).
// Distance argmin bit-exactly emulates the numpy fp32 reference:
//   dist = pairwise_sum(x*x) - 2*(sgemm single-FMA-chain) + pairwise_sum(w*w)
// R2-R4: 128x128 tiles, 8x8 acc, K-split x16, dbuf pipeline, one
//        __syncthreads/step -> 822us, VALUBusy 83%, occ 38%.
// R5/R6: 256x128 tile (16x8 acc) cut LDS/FMA but capped occupancy at
//        2 waves/SIMD (256 regs) -> 30% idle, 887us. REVERTED.
//   Model: dur ~ (FMA + overhead-VALU)/busy. R4 overhead = 0.56 VALU/FMA,
//   suspect = av[]/bw[] local-array formation (v_mov per element).
// R7: R4 geometry exactly, inner loop rewritten as explicit float4
//     component FMAs (macro, no local arrays) so FMAs consume the
//     ds_read_b128 dest regs directly. Chain order per (row,code)
//     unchanged (one FMA per dd, dd ascending) => bit-exact argmin.

#define NTOK 16384
#define KC   8192
#define DD   256

#define OFF_Q    0
#define OFF_LOSS 4194304
#define OFF_IDX  4194305
#define OFF_W    4210689
#define OFF_CS   6307841
#define OFF_EMA  6316033

#define DECAY_F  0.99f
#define OMD_F    0.01f
#define EPS_F    1e-5f
#define KEPS_F   0.08192f   // K * eps

#define SPLIT    16
#define NSTEP    64         // (KC/SPLIT/128) kt-tiles * 16 d-chunks

typedef __attribute__((address_space(3))) unsigned int lds_u;
typedef const __attribute__((address_space(1))) unsigned int glob_u;

// ---------------- 32x32 LDS transpose (coalesced both sides) ---------------
__global__ __launch_bounds__(256) void k_tr(const float* __restrict__ in,
                                            float* __restrict__ outT,
                                            int R, int C) {
    __shared__ float s[32][33];
    const int tx = threadIdx.x & 31, ty = threadIdx.x >> 5;
    const int c0 = blockIdx.x * 32, r0 = blockIdx.y * 32;
    #pragma unroll
    for (int i = 0; i < 4; ++i)
        s[ty + i * 8][tx] = in[(size_t)(r0 + ty + i * 8) * C + c0 + tx];
    __syncthreads();
    #pragma unroll
    for (int i = 0; i < 4; ++i)
        outT[(size_t)(c0 + ty + i * 8) * R + r0 + tx] = s[tx][ty + i * 8];
}

// ---- numpy-pairwise row squared-norms (n=256): two 128 halves, 8 strided
// accumulators each, butterfly combine — bit-exact vs numpy pairwise sum.
__global__ __launch_bounds__(256) void k_rownorm(const float* __restrict__ a,
                                                 float* __restrict__ outn) {
    const int wave = threadIdx.x >> 6, lane = threadIdx.x & 63;
    const int row  = blockIdx.x * 16 + wave * 4 + (lane >> 4);
    const int p    = lane & 15;
    const int h    = p >> 3, j = p & 7;
    const float* base = a + row * DD + h * 128 + j;
    float v = base[0];
    float r = __fmul_rn(v, v);
    #pragma unroll
    for (int t = 1; t < 16; ++t) {
        v = base[8 * t];
        r = __fadd_rn(r, __fmul_rn(v, v));
    }
    r = __fadd_rn(r, __shfl_xor(r, 1));
    r = __fadd_rn(r, __shfl_xor(r, 2));
    r = __fadd_rn(r, __shfl_xor(r, 4));
    r = __fadd_rn(r, __shfl_xor(r, 8));
    if (p == 0) outn[row] = r;
}

// ---------------- argmin: K-split fp32 GEMM, 128 rows x 128 codes/tile -----
// grid = 2048: split = blockIdx&15 (split&7 = XCD id: its two 512KB wT
// chunks stay L2-resident), rb = blockIdx>>4. Each block: 4 code tiles x
// full D, pipelined in 64 flattened (kt,dt) steps with 16-row d-chunks,
// double-buffered LDS, one __syncthreads per step. 8x8 acc per thread.
// acc[i][j] = single fp32 FMA chain over k ascending (BLAS-exact).
__global__ __launch_bounds__(256, 4) void k_argmin(
        const float* __restrict__ zT, const float* __restrict__ wT,
        const float* __restrict__ x2v, const float* __restrict__ w2v,
        float* __restrict__ vbuf, int* __restrict__ kbuf) {
    __shared__ float Zs[2][16][128];   // [buf][d][row]  2 x 8 KB
    __shared__ float Ws[2][16][128];   // [buf][d][code] 2 x 8 KB

    const int tid   = threadIdx.x;
    const int split = blockIdx.x & 15;
    const int rb    = blockIdx.x >> 4;
    const int n0    = rb * 128;
    const int cbase = split * 512;
    const int tx4   = (tid & 15) * 4;
    const int ty4   = (tid >> 4) * 4;
    const int l     = tid & 63;
    const int wv    = tid >> 6;
    const int col   = (l & 31) * 4;

    float bestv[8];
    int   bestk[8];
    #pragma unroll
    for (int i = 0; i < 8; ++i) { bestv[i] = 1e30f; bestk[i] = 0; }

    float acc[8][8];

    // stage step s into buffer b: 4 global_load_lds per wave
    // (wave wv covers d-rows [wv*4, wv*4+4) of the 16-row chunk, 2 rows/load)
    auto stage = [&](int s, int b) {
        const int d0 = (s & 15) * 16;
        const int c0 = cbase + (s >> 4) * 128;
        #pragma unroll
        for (int q = 0; q < 2; ++q) {
            const int r  = wv * 4 + 2 * q;      // wave-uniform base row
            const int rr = r + (l >> 5);        // per-lane row
            const float* gz = zT + (size_t)(d0 + rr) * NTOK + n0 + col;
            const float* gw = wT + (size_t)(d0 + rr) * KC   + c0 + col;
            __builtin_amdgcn_global_load_lds(
                (glob_u*)gz,
                (lds_u*)((char*)&Zs[b][0][0] + r * 512 + l * 16), 16, 0, 0);
            __builtin_amdgcn_global_load_lds(
                (glob_u*)gw,
                (lds_u*)((char*)&Ws[b][0][0] + r * 512 + l * 16), 16, 0, 0);
        }
    };

    stage(0, 0);
    __syncthreads();

    for (int s = 0; s < NSTEP; ++s) {
        const int cur = s & 1;

        if ((s & 15) == 0) {
            #pragma unroll
            for (int i = 0; i < 8; ++i)
                #pragma unroll
                for (int j = 0; j < 8; ++j) acc[i][j] = 0.0f;
        }

        if (s + 1 < NSTEP) stage(s + 1, cur ^ 1);   // prefetch next chunk

        #pragma unroll 8
        for (int dd = 0; dd < 16; ++dd) {
            const float4 a0 = *(const float4*)&Zs[cur][dd][ty4];
            const float4 a1 = *(const float4*)&Zs[cur][dd][64 + ty4];
            const float4 b0 = *(const float4*)&Ws[cur][dd][tx4];
            const float4 b1 = *(const float4*)&Ws[cur][dd][64 + tx4];
            // explicit component FMAs: no local arrays, FMAs read the
            // ds_read_b128 destination registers directly (zero v_mov).
#define FMA_ROW(I, AV)                                   \
            acc[I][0] = __fmaf_rn(AV, b0.x, acc[I][0]);  \
            acc[I][1] = __fmaf_rn(AV, b0.y, acc[I][1]);  \
            acc[I][2] = __fmaf_rn(AV, b0.z, acc[I][2]);  \
            acc[I][3] = __fmaf_rn(AV, b0.w, acc[I][3]);  \
            acc[I][4] = __fmaf_rn(AV, b1.x, acc[I][4]);  \
            acc[I][5] = __fmaf_rn(AV, b1.y, acc[I][5]);  \
            acc[I][6] = __fmaf_rn(AV, b1.z, acc[I][6]);  \
            acc[I][7] = __fmaf_rn(AV, b1.w, acc[I][7]);
            FMA_ROW(0, a0.x)
            FMA_ROW(1, a0.y)
            FMA_ROW(2, a0.z)
            FMA_ROW(3, a0.w)
            FMA_ROW(4, a1.x)
            FMA_ROW(5, a1.y)
            FMA_ROW(6, a1.z)
            FMA_ROW(7, a1.w)
#undef FMA_ROW
        }

        if ((s & 15) == 15) {
            // dist = (x2 - 2*xe) + w2, per-op fp32 rounding; explicit (==, k<)
            // tie-break == np.argmin first-occurrence.
            const int c0 = cbase + (s >> 4) * 128;
            #pragma unroll
            for (int j = 0; j < 8; ++j) {
                const int   code = c0 + ((j < 4) ? (tx4 + j) : (64 + tx4 + j - 4));
                const float w2   = w2v[code];
                #pragma unroll
                for (int i = 0; i < 8; ++i) {
                    const int   row = n0 + ((i < 4) ? (ty4 + i) : (64 + ty4 + i - 4));
                    const float x2  = x2v[row];
                    const float dv  = __fadd_rn(
                        __fsub_rn(x2, __fmul_rn(2.0f, acc[i][j])), w2);
                    if (dv < bestv[i] || (dv == bestv[i] && code < bestk[i])) {
                        bestv[i] = dv; bestk[i] = code;
                    }
                }
            }
        }

        // drains the prefetch (vmcnt) issued BEFORE the ~2k-cycle FMA phase
        // (latency hidden) and the LDS reads (lgkmcnt); releases buffers.
        __syncthreads();
    }

    // reduce across tx (16 consecutive lanes share ty)
    #pragma unroll
    for (int i = 0; i < 8; ++i) {
        float bv = bestv[i];
        int   bk = bestk[i];
        #pragma unroll
        for (int off = 8; off; off >>= 1) {
            const float ov = __shfl_down(bv, off, 16);
            const int   ok = __shfl_down(bk, off, 16);
            if (ov < bv || (ov == bv && ok < bk)) { bv = ov; bk = ok; }
        }
        if ((tid & 15) == 0) {
            const int row = n0 + ((i < 4) ? (ty4 + i) : (64 + ty4 + i - 4));
            vbuf[split * NTOK + row] = bv;
            kbuf[split * NTOK + row] = bk;
        }
    }
}

// ---------------- combine the 16 split-candidates per row ------------------
__global__ __launch_bounds__(256) void k_reduce(const float* __restrict__ vbuf,
                                                const int* __restrict__ kbuf,
                                                int* __restrict__ idx_ws,
                                                float* __restrict__ out) {
    const int r = blockIdx.x * 256 + threadIdx.x;
    float bv = vbuf[r];
    int   bk = kbuf[r];
    #pragma unroll
    for (int s = 1; s < SPLIT; ++s) {
        const float v = vbuf[s * NTOK + r];
        const int   k = kbuf[s * NTOK + r];
        if (v < bv || (v == bv && k < bk)) { bv = v; bk = k; }
    }
    idx_ws[r] = bk;
    out[OFF_IDX + r] = (float)bk;
}

// ---------------- init EMA outputs + zero loss accumulator -----------------
// (runs AFTER k_reduce: OFF_EMA region doubles as vbuf/kbuf scratch)
__global__ __launch_bounds__(256) void k_init(const float* __restrict__ emaw,
                                              const float* __restrict__ ecs,
                                              float* __restrict__ out,
                                              float* __restrict__ lossacc) {
    const int i = blockIdx.x * 256 + threadIdx.x;    // grid covers KC*DD = 2M
    out[OFF_EMA + i] = __fmul_rn(DECAY_F, emaw[i]);
    if (i < KC) out[OFF_CS + i] = __fmul_rn(DECAY_F, ecs[i]);
    if (i == 0) *lossacc = 0.0f;
}

// ---------------- gather quantized + loss partial + EMA scatter ------------
__global__ __launch_bounds__(256) void k_scatter(const float* __restrict__ z,
                                                 const float* __restrict__ w,
                                                 const int* __restrict__ idx_ws,
                                                 float* __restrict__ out,
                                                 float* __restrict__ lossacc) {
    const int n = blockIdx.x, d = threadIdx.x;
    const int k = idx_ws[n];
    const float zv   = z[n * DD + d];
    const float q    = w[k * DD + d];
    const float diff = __fsub_rn(q, zv);
    out[OFF_Q + n * DD + d] = __fadd_rn(zv, diff);   // straight-through value

    float s = __fmul_rn(diff, diff);
    #pragma unroll
    for (int off = 32; off; off >>= 1) s += __shfl_down(s, off, 64);
    __shared__ float ps[4];
    if ((d & 63) == 0) ps[d >> 6] = s;
    __syncthreads();
    if (d == 0) atomicAdd(lossacc, ps[0] + ps[1] + ps[2] + ps[3]);

    atomicAdd(&out[OFF_EMA + k * DD + d], __fmul_rn(OMD_F, zv));
    if (d == 0) atomicAdd(&out[OFF_CS + k], OMD_F);
}

// ---------------- n = sum(new_cluster_size); finalize loss -----------------
__global__ __launch_bounds__(256) void k_nsum(float* __restrict__ out,
                                              const float* __restrict__ lossacc,
                                              float* __restrict__ nsum) {
    const int t = threadIdx.x;
    float s = 0.0f;
    for (int i = t; i < KC; i += 256) s += out[OFF_CS + i];
    #pragma unroll
    for (int off = 32; off; off >>= 1) s += __shfl_down(s, off, 64);
    __shared__ float ps[4];
    if ((t & 63) == 0) ps[t >> 6] = s;
    __syncthreads();
    if (t == 0) {
        *nsum = ps[0] + ps[1] + ps[2] + ps[3];
        out[OFF_LOSS] = 1.25f * (*lossacc) / 4194304.0f;
    }
}

// ---------------- new_weight = new_ema_w / laplace(cluster_size) -----------
__global__ __launch_bounds__(256) void k_neww(float* __restrict__ out,
                                              const float* __restrict__ nsum) {
    const int k = blockIdx.x, d = threadIdx.x;
    const float n  = *nsum;
    const float cs = __fmul_rn(__fdiv_rn(__fadd_rn(out[OFF_CS + k], EPS_F),
                                         __fadd_rn(n, KEPS_F)), n);
    out[OFF_W + k * DD + d] = __fdiv_rn(out[OFF_EMA + k * DD + d], cs);
}

extern "C" void kernel_launch(void* const* d_in, const int* in_sizes, int n_in,
                              void* d_out, int out_size, void* d_ws, size_t ws_size,
                              hipStream_t stream) {
    const float* z    = (const float*)d_in[0];
    const float* w    = (const float*)d_in[1];
    const float* ecs  = (const float*)d_in[2];
    const float* emaw = (const float*)d_in[3];
    float* out = (float*)d_out;

    // small scratch in ws (same footprint that already passed)
    int*   idx_ws  = (int*)d_ws;                       // NTOK ints
    float* x2v     = (float*)d_ws + NTOK;              // NTOK floats
    float* w2v     = x2v + NTOK;                       // KC floats
    float* lossacc = w2v + KC;                         // 1 float
    float* nsum    = lossacc + 1;                      // 1 float

    // big scratch inside not-yet-final d_out regions:
    float* zT   = out + OFF_Q;     // 16384x256 -> 256x16384 (16 MB)
    float* wT   = out + OFF_W;     //  8192x256 -> 256x8192  ( 8 MB)
    float* vbuf = out + OFF_EMA;                        // SPLIT*NTOK floats (1 MB)
    int*   kbuf = (int*)(out + OFF_EMA) + SPLIT * NTOK; // SPLIT*NTOK ints   (1 MB)

    k_tr     <<<dim3(8, 512),     256, 0, stream>>>(z, zT, NTOK, DD);
    k_tr     <<<dim3(8, 256),     256, 0, stream>>>(w, wT, KC, DD);
    k_rownorm<<<NTOK / 16,        256, 0, stream>>>(z, x2v);
    k_rownorm<<<KC / 16,          256, 0, stream>>>(w, w2v);
    k_argmin <<<SPLIT * (NTOK / 128), 256, 0, stream>>>(zT, wT, x2v, w2v, vbuf, kbuf);
    k_reduce <<<NTOK / 256,       256, 0, stream>>>(vbuf, kbuf, idx_ws, out);
    k_init   <<<(KC * DD) / 256,  256, 0, stream>>>(emaw, ecs, out, lossacc);
    k_scatter<<<NTOK,             256, 0, stream>>>(z, w, idx_ws, out, lossacc);
    k_nsum   <<<1,                256, 0, stream>>>(out, lossacc, nsum);
    k_neww   <<<KC,               256, 0, stream>>>(out, nsum);
}

// Round 6
// 1114.092 us; speedup vs baseline: 1.0092x; 1.0092x over previous
//
#include <hip/hip_runtime.h>

// VQ-VAE VectorQuantizer forward + EMA update, MI355X (gfx950).
// Distance argmin bit-exactly emulates the numpy fp32 reference:
//   dist = pairwise_sum(x*x) - 2*(sgemm single-FMA-chain) + pairwise_sum(w*w)
// R2-R4: 128x128 tiles, 8x8 acc, K-split x16, dbuf pipeline -> 822us,
//        VALUBusy 83%, occ 38%.
// R5/R6: 256x128 tile: fewer LDS reads/FMA but 2 waves/SIMD -> 887us. Rev.
// R7: explicit component FMAs: NEUTRAL (829us) — no mov tax existed.
//     Cluster at ~1.9x the 437us fp32-FMA issue floor is robust.
// R8: v_pk_fma_f32 (VOP3P packed fp32): one instruction = two independent
//     IEEE-rounded fp32 FMAs -> halves FMA issue slots (and, if CDNA4 keeps
//     CDNA2/3 dual-rate packed fp32, halves FMA cycles: floor 437->219us).
//     Columns (j,j+1) pair into one pk op; each (row,code) chain is still
//     one fma per k, k ascending; A-broadcast via op_sel (no splat movs).
//     Rounding identical to v_fma_f32 => argmin bit-exact.

#define NTOK 16384
#define KC   8192
#define DD   256

#define OFF_Q    0
#define OFF_LOSS 4194304
#define OFF_IDX  4194305
#define OFF_W    4210689
#define OFF_CS   6307841
#define OFF_EMA  6316033

#define DECAY_F  0.99f
#define OMD_F    0.01f
#define EPS_F    1e-5f
#define KEPS_F   0.08192f   // K * eps

#define SPLIT    16
#define NSTEP    64         // (KC/SPLIT/128) kt-tiles * 16 d-chunks

typedef __attribute__((address_space(3))) unsigned int lds_u;
typedef const __attribute__((address_space(1))) unsigned int glob_u;
typedef float v2f __attribute__((ext_vector_type(2)));
typedef union { float4 f4; v2f h[2]; } f4u;

// ---------------- 32x32 LDS transpose (coalesced both sides) ---------------
__global__ __launch_bounds__(256) void k_tr(const float* __restrict__ in,
                                            float* __restrict__ outT,
                                            int R, int C) {
    __shared__ float s[32][33];
    const int tx = threadIdx.x & 31, ty = threadIdx.x >> 5;
    const int c0 = blockIdx.x * 32, r0 = blockIdx.y * 32;
    #pragma unroll
    for (int i = 0; i < 4; ++i)
        s[ty + i * 8][tx] = in[(size_t)(r0 + ty + i * 8) * C + c0 + tx];
    __syncthreads();
    #pragma unroll
    for (int i = 0; i < 4; ++i)
        outT[(size_t)(c0 + ty + i * 8) * R + r0 + tx] = s[tx][ty + i * 8];
}

// ---- numpy-pairwise row squared-norms (n=256): two 128 halves, 8 strided
// accumulators each, butterfly combine — bit-exact vs numpy pairwise sum.
__global__ __launch_bounds__(256) void k_rownorm(const float* __restrict__ a,
                                                 float* __restrict__ outn) {
    const int wave = threadIdx.x >> 6, lane = threadIdx.x & 63;
    const int row  = blockIdx.x * 16 + wave * 4 + (lane >> 4);
    const int p    = lane & 15;
    const int h    = p >> 3, j = p & 7;
    const float* base = a + row * DD + h * 128 + j;
    float v = base[0];
    float r = __fmul_rn(v, v);
    #pragma unroll
    for (int t = 1; t < 16; ++t) {
        v = base[8 * t];
        r = __fadd_rn(r, __fmul_rn(v, v));
    }
    r = __fadd_rn(r, __shfl_xor(r, 1));
    r = __fadd_rn(r, __shfl_xor(r, 2));
    r = __fadd_rn(r, __shfl_xor(r, 4));
    r = __fadd_rn(r, __shfl_xor(r, 8));
    if (p == 0) outn[row] = r;
}

// ---------------- argmin: K-split fp32 GEMM, 128 rows x 128 codes/tile -----
// grid = 2048: split = blockIdx&15 (split&7 = XCD id: its two 512KB wT
// chunks stay L2-resident), rb = blockIdx>>4. Each block: 4 code tiles x
// full D, pipelined in 64 flattened (kt,dt) steps with 16-row d-chunks,
// double-buffered LDS, one __syncthreads per step. 8x8 acc per thread,
// held as 8x4 v2f pairs fed by v_pk_fma_f32.
__global__ __launch_bounds__(256, 4) void k_argmin(
        const float* __restrict__ zT, const float* __restrict__ wT,
        const float* __restrict__ x2v, const float* __restrict__ w2v,
        float* __restrict__ vbuf, int* __restrict__ kbuf) {
    __shared__ float Zs[2][16][128];   // [buf][d][row]  2 x 8 KB
    __shared__ float Ws[2][16][128];   // [buf][d][code] 2 x 8 KB

    const int tid   = threadIdx.x;
    const int split = blockIdx.x & 15;
    const int rb    = blockIdx.x >> 4;
    const int n0    = rb * 128;
    const int cbase = split * 512;
    const int tx4   = (tid & 15) * 4;
    const int ty4   = (tid >> 4) * 4;
    const int l     = tid & 63;
    const int wv    = tid >> 6;
    const int col   = (l & 31) * 4;

    float bestv[8];
    int   bestk[8];
    #pragma unroll
    for (int i = 0; i < 8; ++i) { bestv[i] = 1e30f; bestk[i] = 0; }

    v2f acc[8][4];

    // stage step s into buffer b: 4 global_load_lds per wave
    // (wave wv covers d-rows [wv*4, wv*4+4) of the 16-row chunk, 2 rows/load)
    auto stage = [&](int s, int b) {
        const int d0 = (s & 15) * 16;
        const int c0 = cbase + (s >> 4) * 128;
        #pragma unroll
        for (int q = 0; q < 2; ++q) {
            const int r  = wv * 4 + 2 * q;      // wave-uniform base row
            const int rr = r + (l >> 5);        // per-lane row
            const float* gz = zT + (size_t)(d0 + rr) * NTOK + n0 + col;
            const float* gw = wT + (size_t)(d0 + rr) * KC   + c0 + col;
            __builtin_amdgcn_global_load_lds(
                (glob_u*)gz,
                (lds_u*)((char*)&Zs[b][0][0] + r * 512 + l * 16), 16, 0, 0);
            __builtin_amdgcn_global_load_lds(
                (glob_u*)gw,
                (lds_u*)((char*)&Ws[b][0][0] + r * 512 + l * 16), 16, 0, 0);
        }
    };

    stage(0, 0);
    __syncthreads();

    for (int s = 0; s < NSTEP; ++s) {
        const int cur = s & 1;

        if ((s & 15) == 0) {
            #pragma unroll
            for (int i = 0; i < 8; ++i)
                #pragma unroll
                for (int jp = 0; jp < 4; ++jp) acc[i][jp] = (v2f)(0.0f);
        }

        if (s + 1 < NSTEP) stage(s + 1, cur ^ 1);   // prefetch next chunk

        #pragma unroll 8
        for (int dd = 0; dd < 16; ++dd) {
            f4u A0, A1, B0, B1;
            A0.f4 = *(const float4*)&Zs[cur][dd][ty4];
            A1.f4 = *(const float4*)&Zs[cur][dd][64 + ty4];
            B0.f4 = *(const float4*)&Ws[cur][dd][tx4];
            B1.f4 = *(const float4*)&Ws[cur][dd][64 + tx4];
            // v_pk_fma_f32: two independent fp32 FMAs per instruction.
            // A-broadcast via op_sel on the pair (no splat movs):
            //   LO: both halves read src0.lo;  HI: both halves read src0.hi.
#define PKLO(ACC, A, B) asm("v_pk_fma_f32 %0, %1, %2, %0 op_sel:[0,0,0] op_sel_hi:[0,1,1]" \
                            : "+v"(ACC) : "v"(A), "v"(B))
#define PKHI(ACC, A, B) asm("v_pk_fma_f32 %0, %1, %2, %0 op_sel:[1,0,0] op_sel_hi:[1,1,1]" \
                            : "+v"(ACC) : "v"(A), "v"(B))
#define PK4(MAC, I, AP)                \
            MAC(acc[I][0], AP, B0.h[0]); \
            MAC(acc[I][1], AP, B0.h[1]); \
            MAC(acc[I][2], AP, B1.h[0]); \
            MAC(acc[I][3], AP, B1.h[1]);
            PK4(PKLO, 0, A0.h[0])
            PK4(PKHI, 1, A0.h[0])
            PK4(PKLO, 2, A0.h[1])
            PK4(PKHI, 3, A0.h[1])
            PK4(PKLO, 4, A1.h[0])
            PK4(PKHI, 5, A1.h[0])
            PK4(PKLO, 6, A1.h[1])
            PK4(PKHI, 7, A1.h[1])
#undef PK4
#undef PKHI
#undef PKLO
        }

        if ((s & 15) == 15) {
            // dist = (x2 - 2*xe) + w2, per-op fp32 rounding; explicit (==, k<)
            // tie-break == np.argmin first-occurrence (order-independent).
            const int c0 = cbase + (s >> 4) * 128;
            #pragma unroll
            for (int j = 0; j < 8; ++j) {
                const int   jp   = j >> 1;
                const int   code = c0 + ((j < 4) ? (tx4 + j) : (64 + tx4 + j - 4));
                const float w2   = w2v[code];
                #pragma unroll
                for (int i = 0; i < 8; ++i) {
                    const int   row = n0 + ((i < 4) ? (ty4 + i) : (64 + ty4 + i - 4));
                    const float x2  = x2v[row];
                    const float xe  = (j & 1) ? acc[i][jp].y : acc[i][jp].x;
                    const float dv  = __fadd_rn(
                        __fsub_rn(x2, __fmul_rn(2.0f, xe)), w2);
                    if (dv < bestv[i] || (dv == bestv[i] && code < bestk[i])) {
                        bestv[i] = dv; bestk[i] = code;
                    }
                }
            }
        }

        // drains the prefetch (vmcnt) issued BEFORE the FMA phase
        // (latency hidden) and the LDS reads (lgkmcnt); releases buffers.
        __syncthreads();
    }

    // reduce across tx (16 consecutive lanes share ty)
    #pragma unroll
    for (int i = 0; i < 8; ++i) {
        float bv = bestv[i];
        int   bk = bestk[i];
        #pragma unroll
        for (int off = 8; off; off >>= 1) {
            const float ov = __shfl_down(bv, off, 16);
            const int   ok = __shfl_down(bk, off, 16);
            if (ov < bv || (ov == bv && ok < bk)) { bv = ov; bk = ok; }
        }
        if ((tid & 15) == 0) {
            const int row = n0 + ((i < 4) ? (ty4 + i) : (64 + ty4 + i - 4));
            vbuf[split * NTOK + row] = bv;
            kbuf[split * NTOK + row] = bk;
        }
    }
}

// ---------------- combine the 16 split-candidates per row ------------------
__global__ __launch_bounds__(256) void k_reduce(const float* __restrict__ vbuf,
                                                const int* __restrict__ kbuf,
                                                int* __restrict__ idx_ws,
                                                float* __restrict__ out) {
    const int r = blockIdx.x * 256 + threadIdx.x;
    float bv = vbuf[r];
    int   bk = kbuf[r];
    #pragma unroll
    for (int s = 1; s < SPLIT; ++s) {
        const float v = vbuf[s * NTOK + r];
        const int   k = kbuf[s * NTOK + r];
        if (v < bv || (v == bv && k < bk)) { bv = v; bk = k; }
    }
    idx_ws[r] = bk;
    out[OFF_IDX + r] = (float)bk;
}

// ---------------- init EMA outputs + zero loss accumulator -----------------
// (runs AFTER k_reduce: OFF_EMA region doubles as vbuf/kbuf scratch)
__global__ __launch_bounds__(256) void k_init(const float* __restrict__ emaw,
                                              const float* __restrict__ ecs,
                                              float* __restrict__ out,
                                              float* __restrict__ lossacc) {
    const int i = blockIdx.x * 256 + threadIdx.x;    // grid covers KC*DD = 2M
    out[OFF_EMA + i] = __fmul_rn(DECAY_F, emaw[i]);
    if (i < KC) out[OFF_CS + i] = __fmul_rn(DECAY_F, ecs[i]);
    if (i == 0) *lossacc = 0.0f;
}

// ---------------- gather quantized + loss partial + EMA scatter ------------
__global__ __launch_bounds__(256) void k_scatter(const float* __restrict__ z,
                                                 const float* __restrict__ w,
                                                 const int* __restrict__ idx_ws,
                                                 float* __restrict__ out,
                                                 float* __restrict__ lossacc) {
    const int n = blockIdx.x, d = threadIdx.x;
    const int k = idx_ws[n];
    const float zv   = z[n * DD + d];
    const float q    = w[k * DD + d];
    const float diff = __fsub_rn(q, zv);
    out[OFF_Q + n * DD + d] = __fadd_rn(zv, diff);   // straight-through value

    float s = __fmul_rn(diff, diff);
    #pragma unroll
    for (int off = 32; off; off >>= 1) s += __shfl_down(s, off, 64);
    __shared__ float ps[4];
    if ((d & 63) == 0) ps[d >> 6] = s;
    __syncthreads();
    if (d == 0) atomicAdd(lossacc, ps[0] + ps[1] + ps[2] + ps[3]);

    atomicAdd(&out[OFF_EMA + k * DD + d], __fmul_rn(OMD_F, zv));
    if (d == 0) atomicAdd(&out[OFF_CS + k], OMD_F);
}

// ---------------- n = sum(new_cluster_size); finalize loss -----------------
__global__ __launch_bounds__(256) void k_nsum(float* __restrict__ out,
                                              const float* __restrict__ lossacc,
                                              float* __restrict__ nsum) {
    const int t = threadIdx.x;
    float s = 0.0f;
    for (int i = t; i < KC; i += 256) s += out[OFF_CS + i];
    #pragma unroll
    for (int off = 32; off; off >>= 1) s += __shfl_down(s, off, 64);
    __shared__ float ps[4];
    if ((t & 63) == 0) ps[t >> 6] = s;
    __syncthreads();
    if (t == 0) {
        *nsum = ps[0] + ps[1] + ps[2] + ps[3];
        out[OFF_LOSS] = 1.25f * (*lossacc) / 4194304.0f;
    }
}

// ---------------- new_weight = new_ema_w / laplace(cluster_size) -----------
__global__ __launch_bounds__(256) void k_neww(float* __restrict__ out,
                                              const float* __restrict__ nsum) {
    const int k = blockIdx.x, d = threadIdx.x;
    const float n  = *nsum;
    const float cs = __fmul_rn(__fdiv_rn(__fadd_rn(out[OFF_CS + k], EPS_F),
                                         __fadd_rn(n, KEPS_F)), n);
    out[OFF_W + k * DD + d] = __fdiv_rn(out[OFF_EMA + k * DD + d], cs);
}

extern "C" void kernel_launch(void* const* d_in, const int* in_sizes, int n_in,
                              void* d_out, int out_size, void* d_ws, size_t ws_size,
                              hipStream_t stream) {
    const float* z    = (const float*)d_in[0];
    const float* w    = (const float*)d_in[1];
    const float* ecs  = (const float*)d_in[2];
    const float* emaw = (const float*)d_in[3];
    float* out = (float*)d_out;

    // small scratch in ws (same footprint that already passed)
    int*   idx_ws  = (int*)d_ws;                       // NTOK ints
    float* x2v     = (float*)d_ws + NTOK;              // NTOK floats
    float* w2v     = x2v + NTOK;                       // KC floats
    float* lossacc = w2v + KC;                         // 1 float
    float* nsum    = lossacc + 1;                      // 1 float

    // big scratch inside not-yet-final d_out regions:
    float* zT   = out + OFF_Q;     // 16384x256 -> 256x16384 (16 MB)
    float* wT   = out + OFF_W;     //  8192x256 -> 256x8192  ( 8 MB)
    float* vbuf = out + OFF_EMA;                        // SPLIT*NTOK floats (1 MB)
    int*   kbuf = (int*)(out + OFF_EMA) + SPLIT * NTOK; // SPLIT*NTOK ints   (1 MB)

    k_tr     <<<dim3(8, 512),     256, 0, stream>>>(z, zT, NTOK, DD);
    k_tr     <<<dim3(8, 256),     256, 0, stream>>>(w, wT, KC, DD);
    k_rownorm<<<NTOK / 16,        256, 0, stream>>>(z, x2v);
    k_rownorm<<<KC / 16,          256, 0, stream>>>(w, w2v);
    k_argmin <<<SPLIT * (NTOK / 128), 256, 0, stream>>>(zT, wT, x2v, w2v, vbuf, kbuf);
    k_reduce <<<NTOK / 256,       256, 0, stream>>>(vbuf, kbuf, idx_ws, out);
    k_init   <<<(KC * DD) / 256,  256, 0, stream>>>(emaw, ecs, out, lossacc);
    k_scatter<<<NTOK,             256, 0, stream>>>(z, w, idx_ws, out, lossacc);
    k_nsum   <<<1,                256, 0, stream>>>(out, lossacc, nsum);
    k_neww   <<<KC,               256, 0, stream>>>(out, nsum);
}